// Round 3
// baseline (335.887 us; speedup 1.0000x reference)
//
#include <hip/hip_runtime.h>
#include <hip/hip_bf16.h>

// B=4096, T=200, D=64, H=32 attention pooling with score MLP.
// score(b,t) = W2 . sigmoid( qa[b] + k_t @ Wk ),  Wk = W1b - W1c   (b2 softmax-invariant)
// qa[b][j]  = b1[j] + q_b @ (W1a + W1c)[:,j]
// Score GEMM per row: [200x64]@[64x32] -> mfma_f32_16x16x32_bf16 (13 M-tiles, 2 N-tiles, 2 K-steps).

#define B 4096
#define T 200
#define D 64
#define H 32
#define TP 208        // T padded to 13 * 16
#define KP 72         // LDS key-row pitch in bf16 units (144 B: 16B-aligned, 2-way max bank aliasing)

typedef __attribute__((ext_vector_type(8))) short short8;   // 8 bf16 = 4 VGPRs (MFMA A/B frag)
typedef __attribute__((ext_vector_type(4))) float f32x4;    // MFMA C/D frag

// ws layout (floats): [0, B*H) qa ; then 2048 bf16 (1024 floats) wk fragments
// wkf flat order: element e of fragment (fs = ntile*2+kstep), lane l:
//   wkf[(fs*64 + l)*8 + e] = Wk[k = kstep*32 + (l>>4)*8 + e][n = ntile*16 + (l&15)]  (bf16)

__global__ __launch_bounds__(256) void prep_kernel(
        const float* __restrict__ W1,     // [192,32]
        const float* __restrict__ b1,     // [32]
        const float* __restrict__ query,  // [B,1,D]
        float*       __restrict__ qa_ws,  // [B,32]
        unsigned short* __restrict__ wkf) // [2048] bf16
{
    int blk = blockIdx.x;
    int n = blk * 256 + threadIdx.x;
    if (blk < (B * H) / 256) {
        int b = n >> 5;
        int j = n & 31;
        const float* qb = query + (size_t)b * D;
        float acc = b1[j];
        #pragma unroll 8
        for (int i = 0; i < D; ++i)
            acc = fmaf(qb[i], W1[i * H + j] + W1[(128 + i) * H + j], acc);
        qa_ws[n] = acc;
    } else {
        int m = n - (B * H);              // 0..2047
        int e  = m & 7;
        int l  = (m >> 3) & 63;
        int fs = m >> 9;                  // 0..3
        int ntile = fs >> 1, kstep = fs & 1;
        int k = kstep * 32 + (l >> 4) * 8 + e;     // d index 0..63
        int j = ntile * 16 + (l & 15);             // hidden index 0..31
        float v = W1[(64 + k) * H + j] - W1[(128 + k) * H + j];
        __hip_bfloat16 hv = __float2bfloat16(v);
        wkf[m] = __builtin_bit_cast(unsigned short, hv);
    }
}

__global__ __launch_bounds__(256, 5) void attn_pool_kernel(
        const float* __restrict__ keys,   // [B,T,D] fp32
        const int*   __restrict__ mask,   // [B,T]
        const unsigned short* __restrict__ wkf, // [2048] bf16 B-fragments
        const float* __restrict__ qa_all, // [B,32]
        const float* __restrict__ W2,     // [32]
        float*       __restrict__ out)    // [B,1,D]
{
    __shared__ unsigned short kt[TP * KP];   // 29,952 B bf16 keys tile (A-operand)
    __shared__ float sc_lds[TP];             // raw scores, then softmax weights
    __shared__ float red[8];                 // [0..3] max partials, [4..7] sum partials

    const int tid  = threadIdx.x;
    const int b    = blockIdx.x;
    const int wv   = tid >> 6;
    const int lane = tid & 63;
    const int quad = lane >> 4;
    const int l15  = lane & 15;

    // ---- phase 1: stage keys[b] -> LDS bf16 (coalesced float4 reads) ----
    const float4* kp = reinterpret_cast<const float4*>(keys + (size_t)b * (T * D));
    for (int idx = tid; idx < (T * D) / 4; idx += 256) {
        float4 v = kp[idx];
        int t  = idx >> 4;            // 16 float4 per row
        int i4 = idx & 15;
        __hip_bfloat16 h0 = __float2bfloat16(v.x);
        __hip_bfloat16 h1 = __float2bfloat16(v.y);
        __hip_bfloat16 h2 = __float2bfloat16(v.z);
        __hip_bfloat16 h3 = __float2bfloat16(v.w);
        ushort4 u;
        u.x = __builtin_bit_cast(unsigned short, h0);
        u.y = __builtin_bit_cast(unsigned short, h1);
        u.z = __builtin_bit_cast(unsigned short, h2);
        u.w = __builtin_bit_cast(unsigned short, h3);
        *reinterpret_cast<ushort4*>(&kt[t * KP + i4 * 4]) = u;
    }
    // zero-fill pad rows 200..207 (576 ushorts = 144 ushort4)
    if (tid < 144) {
        ushort4 z; z.x = z.y = z.z = z.w = 0;
        *reinterpret_cast<ushort4*>(&kt[T * KP + tid * 4]) = z;
    }

    // ---- B fragments: load Wk once (16 VGPRs), plus per-lane qa/W2 ----
    const short8* wf = reinterpret_cast<const short8*>(wkf);
    short8 bfrag[4];
    #pragma unroll
    for (int fs = 0; fs < 4; ++fs)
        bfrag[fs] = wf[fs * 64 + lane];

    const float* qa = qa_all + (size_t)b * H;
    float qa0 = qa[l15];
    float qa1 = qa[16 + l15];
    float w20 = W2[l15];
    float w21 = W2[16 + l15];

    __syncthreads();

    // ---- phase 2: MFMA score GEMM + fused sigmoid/W2 epilogue ----
    for (int m0 = wv; m0 < TP / 16; m0 += 4) {
        const int trow = m0 * 16 + l15;
        short8 a0 = *reinterpret_cast<const short8*>(&kt[trow * KP + quad * 8]);
        short8 a1 = *reinterpret_cast<const short8*>(&kt[trow * KP + 32 + quad * 8]);

        f32x4 acc0 = {0.f, 0.f, 0.f, 0.f};
        f32x4 acc1 = {0.f, 0.f, 0.f, 0.f};
        acc0 = __builtin_amdgcn_mfma_f32_16x16x32_bf16(a0, bfrag[0], acc0, 0, 0, 0);
        acc0 = __builtin_amdgcn_mfma_f32_16x16x32_bf16(a1, bfrag[1], acc0, 0, 0, 0);
        acc1 = __builtin_amdgcn_mfma_f32_16x16x32_bf16(a0, bfrag[2], acc1, 0, 0, 0);
        acc1 = __builtin_amdgcn_mfma_f32_16x16x32_bf16(a1, bfrag[3], acc1, 0, 0, 0);

        // D layout: row(t) = quad*4 + r, col(j) = lane&15 (+16 for ntile1)
        #pragma unroll
        for (int r = 0; r < 4; ++r) {
            float x0 = acc0[r] + qa0;
            float x1 = acc1[r] + qa1;
            float s0 = __builtin_amdgcn_rcpf(1.0f + exp2f(-x0 * 1.44269504088896340736f));
            float s1 = __builtin_amdgcn_rcpf(1.0f + exp2f(-x1 * 1.44269504088896340736f));
            float p = fmaf(s0, w20, s1 * w21);
            #pragma unroll
            for (int off = 1; off <= 8; off <<= 1)
                p += __shfl_xor(p, off, 64);     // reduce 16 lanes within quad
            if (l15 == 0)
                sc_lds[m0 * 16 + quad * 4 + r] = p;
        }
    }
    __syncthreads();

    // ---- softmax over t ----
    const int t = tid;
    float s = (t < T) ? ((mask[(size_t)b * T + t] != 0) ? sc_lds[t] : -4294967295.0f)
                      : -INFINITY;

    float m = s;
    #pragma unroll
    for (int off = 32; off >= 1; off >>= 1)
        m = fmaxf(m, __shfl_xor(m, off, 64));
    if (lane == 0) red[wv] = m;
    __syncthreads();
    m = fmaxf(fmaxf(red[0], red[1]), fmaxf(red[2], red[3]));

    float e = (t < T) ? exp2f((s - m) * 1.44269504088896340736f) : 0.0f;
    float tot = e;
    #pragma unroll
    for (int off = 32; off >= 1; off >>= 1)
        tot += __shfl_xor(tot, off, 64);
    if (lane == 0) red[4 + wv] = tot;
    __syncthreads();
    tot = (red[4] + red[5]) + (red[6] + red[7]);

    if (t < T) sc_lds[t] = e * __builtin_amdgcn_rcpf(tot);   // weights
    __syncthreads();

    // ---- phase 3: weighted key sum, fp32 keys re-read from global (L2-hot) ----
    float* part = reinterpret_cast<float*>(kt);   // alias staging buffer (done with it)
    {
        const float* krow = keys + (size_t)b * (T * D);
        float acc = 0.0f;
        const int t0 = wv * 50;
        #pragma unroll 5
        for (int tt = t0; tt < t0 + 50; ++tt)
            acc = fmaf(sc_lds[tt], krow[tt * D + lane], acc);
        part[wv * 64 + lane] = acc;
    }
    __syncthreads();
    if (tid < 64) {
        out[(size_t)b * D + tid] =
            ((part[tid] + part[64 + tid]) + (part[128 + tid] + part[192 + tid]));
    }
}

extern "C" void kernel_launch(void* const* d_in, const int* in_sizes, int n_in,
                              void* d_out, int out_size, void* d_ws, size_t ws_size,
                              hipStream_t stream) {
    const float* query = (const float*)d_in[0];
    const float* keys  = (const float*)d_in[1];
    const int*   mask  = (const int*)d_in[2];
    const float* W1    = (const float*)d_in[3];
    const float* b1    = (const float*)d_in[4];
    const float* W2    = (const float*)d_in[5];
    // d_in[6] = b2: softmax-invariant, unused.

    float* qa = (float*)d_ws;                              // B*H floats
    unsigned short* wkf = (unsigned short*)(qa + B * H);   // 2048 bf16

    prep_kernel<<<(B * H) / 256 + 8, 256, 0, stream>>>(W1, b1, query, qa, wkf);
    attn_pool_kernel<<<B, 256, 0, stream>>>(keys, mask, wkf, qa, W2, (float*)d_out);
}

// Round 4
// 305.092 us; speedup vs baseline: 1.1009x; 1.1009x over previous
//
#include <hip/hip_runtime.h>
#include <hip/hip_bf16.h>

// B=4096, T=200, D=64, H=32 attention pooling with score MLP — single-pass form.
// score(b,t) = W2 . sigmoid( qa[b] + k_t @ Wk ),  Wk = W1b - W1c   (b2 softmax-invariant)
// qa[b][j]  = b1[j] + q_b @ (W1a + W1c)[:,j]
// Softmax via fixed offset: w_t = 2^((s_t-16)*log2e)  (|s| <= sum|W2| ~ 6.3 << 16,
// shift-invariant, masked -> exact 0).  out = (sum_t w_t k_t) / (sum_t w_t).
// One kernel pass over keys; waves independent; single __syncthreads at the end.

#define B 4096
#define T 200
#define D 64
#define H 32
#define LOG2E 1.44269504088896340736f
#define SOFF 16.0f

typedef __attribute__((ext_vector_type(8))) short short8;   // 8 bf16 (MFMA A/B frag)
typedef __attribute__((ext_vector_type(4))) float f32x4;    // MFMA C/D frag

// ws layout (floats): [0, B*H) qa ; then 2048 bf16 wk B-fragments
// wkf[(fs*64 + l)*8 + e] = Wk[k = kstep*32 + (l>>4)*8 + e][n = ntile*16 + (l&15)]
//   with fs = ntile*2 + kstep   (layout verified by R3's passing run)

__global__ __launch_bounds__(256) void prep_kernel(
        const float* __restrict__ W1,     // [192,32]
        const float* __restrict__ b1,     // [32]
        const float* __restrict__ query,  // [B,1,D]
        float*       __restrict__ qa_ws,  // [B,32]
        unsigned short* __restrict__ wkf) // [2048] bf16
{
    int blk = blockIdx.x;
    int n = blk * 256 + threadIdx.x;
    if (blk < (B * H) / 256) {
        int b = n >> 5;
        int j = n & 31;
        const float* qb = query + (size_t)b * D;
        float acc = b1[j];
        #pragma unroll 8
        for (int i = 0; i < D; ++i)
            acc = fmaf(qb[i], W1[i * H + j] + W1[(128 + i) * H + j], acc);
        qa_ws[n] = acc;
    } else {
        int m = n - (B * H);              // 0..2047
        int e  = m & 7;
        int l  = (m >> 3) & 63;
        int fs = m >> 9;                  // 0..3
        int ntile = fs >> 1, kstep = fs & 1;
        int k = kstep * 32 + (l >> 4) * 8 + e;
        int j = ntile * 16 + (l & 15);
        float v = W1[(64 + k) * H + j] - W1[(128 + k) * H + j];
        __hip_bfloat16 hv = __float2bfloat16(v);
        wkf[m] = __builtin_bit_cast(unsigned short, hv);
    }
}

__device__ __forceinline__ unsigned short bf16u(float x) {
    __hip_bfloat16 h = __float2bfloat16(x);
    return __builtin_bit_cast(unsigned short, h);
}

__global__ __launch_bounds__(256, 5) void attn_pool_kernel(
        const float* __restrict__ keys,   // [B,T,D] fp32
        const int*   __restrict__ mask,   // [B,T]
        const unsigned short* __restrict__ wkf, // [2048] bf16 B-fragments
        const float* __restrict__ qa_all, // [B,32]
        const float* __restrict__ W2,     // [32]
        float*       __restrict__ out)    // [B,1,D]
{
    __shared__ float part[4][64];
    __shared__ float denw[4];

    const int tid  = threadIdx.x;
    const int b    = blockIdx.x;
    const int wv   = tid >> 6;
    const int lane = tid & 63;
    const int quad = lane >> 4;
    const int l15  = lane & 15;

    // Wk B-fragments: 16 VGPRs, loaded once (L2-hot, broadcast)
    const short8* wf = reinterpret_cast<const short8*>(wkf);
    short8 bf0 = wf[0 * 64 + lane];
    short8 bf1 = wf[1 * 64 + lane];
    short8 bf2 = wf[2 * 64 + lane];
    short8 bf3 = wf[3 * 64 + lane];

    const float* qa = qa_all + (size_t)b * H;
    const float qa0 = qa[l15];
    const float qa1 = qa[16 + l15];
    const float w20 = W2[l15];
    const float w21 = W2[16 + l15];

    const float4* krow = reinterpret_cast<const float4*>(keys + (size_t)b * (T * D));
    const int*    mrow = mask + (size_t)b * T;

    float acc[16];
    #pragma unroll
    for (int e = 0; e < 16; ++e) acc[e] = 0.0f;
    float den = 0.0f;

    // wave wv handles 16-row tiles m0 = wv, wv+4, wv+8, (12)
    for (int m0 = wv; m0 < 13; m0 += 4) {
        const int t  = m0 * 16 + l15;
        const int tr = (t < T) ? t : (T - 1);      // clamp pad rows (weight forced 0)

        // fp32 key row slice for this lane: d in [quad*8, quad*8+8) u [32+quad*8, ...)
        float4 k0 = krow[tr * 16 + quad * 2 + 0];
        float4 k1 = krow[tr * 16 + quad * 2 + 1];
        float4 k2 = krow[tr * 16 + 8 + quad * 2 + 0];
        float4 k3 = krow[tr * 16 + 8 + quad * 2 + 1];
        int mval = mrow[tr];

        // bf16 A-fragments (A[m=l15][k=quad*8+e] ; second frag k+32)
        short8 a0, a1;
        a0[0] = (short)bf16u(k0.x); a0[1] = (short)bf16u(k0.y);
        a0[2] = (short)bf16u(k0.z); a0[3] = (short)bf16u(k0.w);
        a0[4] = (short)bf16u(k1.x); a0[5] = (short)bf16u(k1.y);
        a0[6] = (short)bf16u(k1.z); a0[7] = (short)bf16u(k1.w);
        a1[0] = (short)bf16u(k2.x); a1[1] = (short)bf16u(k2.y);
        a1[2] = (short)bf16u(k2.z); a1[3] = (short)bf16u(k2.w);
        a1[4] = (short)bf16u(k3.x); a1[5] = (short)bf16u(k3.y);
        a1[6] = (short)bf16u(k3.z); a1[7] = (short)bf16u(k3.w);

        f32x4 c0 = {0.f, 0.f, 0.f, 0.f};
        f32x4 c1 = {0.f, 0.f, 0.f, 0.f};
        c0 = __builtin_amdgcn_mfma_f32_16x16x32_bf16(a0, bf0, c0, 0, 0, 0);
        c0 = __builtin_amdgcn_mfma_f32_16x16x32_bf16(a1, bf1, c0, 0, 0, 0);
        c1 = __builtin_amdgcn_mfma_f32_16x16x32_bf16(a0, bf2, c1, 0, 0, 0);
        c1 = __builtin_amdgcn_mfma_f32_16x16x32_bf16(a1, bf3, c1, 0, 0, 0);

        // sigmoid + W2 contraction; D layout: row t' = quad*4+r, col j = l15
        float p[4];
        #pragma unroll
        for (int r = 0; r < 4; ++r) {
            float x0 = c0[r] + qa0;
            float x1 = c1[r] + qa1;
            float s0 = __builtin_amdgcn_rcpf(1.0f + exp2f(-x0 * LOG2E));
            float s1 = __builtin_amdgcn_rcpf(1.0f + exp2f(-x1 * LOG2E));
            p[r] = fmaf(s0, w20, s1 * w21);
        }
        // reduce over j (16 col-lanes within quad)
        #pragma unroll
        for (int r = 0; r < 4; ++r) {
            #pragma unroll
            for (int off = 1; off <= 8; off <<= 1)
                p[r] += __shfl_xor(p[r], off, 64);
        }
        // route score[t'=l15] to the lane holding k_{t'} (wave-local bpermute,
        // source lane = (l15>>2)*16, reg select r' = l15&3)
        const int addr = (l15 >> 2) << 6;
        int q0 = __builtin_amdgcn_ds_bpermute(addr, __builtin_bit_cast(int, p[0]));
        int q1 = __builtin_amdgcn_ds_bpermute(addr, __builtin_bit_cast(int, p[1]));
        int q2 = __builtin_amdgcn_ds_bpermute(addr, __builtin_bit_cast(int, p[2]));
        int q3 = __builtin_amdgcn_ds_bpermute(addr, __builtin_bit_cast(int, p[3]));
        const int rsel = l15 & 3;
        int s01 = (rsel & 1) ? q1 : q0;
        int s23 = (rsel & 1) ? q3 : q2;
        float st = __builtin_bit_cast(float, (rsel & 2) ? s23 : s01);

        // fixed-offset softmax weight
        float w = ((t < T) && (mval != 0)) ? exp2f((st - SOFF) * LOG2E) : 0.0f;
        den += w;

        acc[0]  = fmaf(w, k0.x, acc[0]);  acc[1]  = fmaf(w, k0.y, acc[1]);
        acc[2]  = fmaf(w, k0.z, acc[2]);  acc[3]  = fmaf(w, k0.w, acc[3]);
        acc[4]  = fmaf(w, k1.x, acc[4]);  acc[5]  = fmaf(w, k1.y, acc[5]);
        acc[6]  = fmaf(w, k1.z, acc[6]);  acc[7]  = fmaf(w, k1.w, acc[7]);
        acc[8]  = fmaf(w, k2.x, acc[8]);  acc[9]  = fmaf(w, k2.y, acc[9]);
        acc[10] = fmaf(w, k2.z, acc[10]); acc[11] = fmaf(w, k2.w, acc[11]);
        acc[12] = fmaf(w, k3.x, acc[12]); acc[13] = fmaf(w, k3.y, acc[13]);
        acc[14] = fmaf(w, k3.z, acc[14]); acc[15] = fmaf(w, k3.w, acc[15]);
    }

    // reduce acc/den over the 16 t-lanes (l15) within each quad
    #pragma unroll
    for (int off = 1; off <= 8; off <<= 1) {
        #pragma unroll
        for (int e = 0; e < 16; ++e)
            acc[e] += __shfl_xor(acc[e], off, 64);
        den += __shfl_xor(den, off, 64);
    }

    if (l15 == 0) {
        #pragma unroll
        for (int e = 0; e < 8; ++e) {
            part[wv][quad * 8 + e]      = acc[e];
            part[wv][32 + quad * 8 + e] = acc[8 + e];
        }
        if (quad == 0) denw[wv] = den;
    }
    __syncthreads();

    if (tid < 64) {
        float dtot = (denw[0] + denw[1]) + (denw[2] + denw[3]);
        float v = (part[0][tid] + part[1][tid]) + (part[2][tid] + part[3][tid]);
        out[(size_t)b * D + tid] = v * __builtin_amdgcn_rcpf(dtot);
    }
}

extern "C" void kernel_launch(void* const* d_in, const int* in_sizes, int n_in,
                              void* d_out, int out_size, void* d_ws, size_t ws_size,
                              hipStream_t stream) {
    const float* query = (const float*)d_in[0];
    const float* keys  = (const float*)d_in[1];
    const int*   mask  = (const int*)d_in[2];
    const float* W1    = (const float*)d_in[3];
    const float* b1    = (const float*)d_in[4];
    const float* W2    = (const float*)d_in[5];
    // d_in[6] = b2: softmax-invariant, unused.

    float* qa = (float*)d_ws;                              // B*H floats
    unsigned short* wkf = (unsigned short*)(qa + B * H);   // 2048 bf16

    prep_kernel<<<(B * H) / 256 + 8, 256, 0, stream>>>(W1, b1, query, qa, wkf);
    attn_pool_kernel<<<B, 256, 0, stream>>>(keys, mask, wkf, qa, W2, (float*)d_out);
}

// Round 5
// 303.970 us; speedup vs baseline: 1.1050x; 1.0037x over previous
//
#include <hip/hip_runtime.h>
#include <hip/hip_bf16.h>

// B=4096, T=200, D=64, H=32 attention pooling with score MLP — fully flattened form.
// score(b,t) = W2 . sigmoid( qa[b] + k_t @ Wk ),  Wk = W1b - W1c   (b2 softmax-invariant)
// qa[b][j]  = b1[j] + q_b @ (W1a + W1c)[:,j]
// Fixed-offset softmax: w_t = 2^((s_t-16)*log2e), |s| <= sum|W2| << 16; masked -> 0.
// out[b] = num[b]/den[b],  num/den accumulated by 53248 independent waves (one 16-row
// tile each) via device-scope f32 atomics. No __syncthreads in the hot kernel.

#define B 4096
#define T 200
#define D 64
#define H 32
#define LOG2E 1.44269504088896340736f
#define SOFF 16.0f
#define NTILE 13
#define PITCH 68            // LDS row pitch (floats): rotates bank groups, 2-way max

typedef __attribute__((ext_vector_type(8))) short short8;   // 8 bf16 (MFMA A/B frag)
typedef __attribute__((ext_vector_type(4))) float f32x4;    // MFMA C/D frag

// ws float layout:
//   [0, 131072)            qa[B][32]
//   [131072, 132096)       wkf: 2048 bf16 B-fragments (1024 floats)
//   [132096, 394240)       num[B][64]   (zeroed by prep)
//   [394240, 398336)       den[B]       (zeroed by prep)

__global__ __launch_bounds__(256) void prep_kernel(
        const float* __restrict__ W1,     // [192,32]
        const float* __restrict__ b1,     // [32]
        const float* __restrict__ query,  // [B,1,D]
        float*       __restrict__ ws)
{
    int blk = blockIdx.x;
    int tid = threadIdx.x;
    if (blk < 512) {                       // qa
        int n = blk * 256 + tid;
        int b = n >> 5;
        int j = n & 31;
        const float* qb = query + (size_t)b * D;
        float acc = b1[j];
        #pragma unroll 8
        for (int i = 0; i < D; ++i)
            acc = fmaf(qb[i], W1[i * H + j] + W1[(128 + i) * H + j], acc);
        ws[n] = acc;
    } else if (blk < 520) {                // wkf B-fragments (layout verified R3/R4)
        int m = (blk - 512) * 256 + tid;   // 0..2047
        int e  = m & 7;
        int l  = (m >> 3) & 63;
        int fs = m >> 9;
        int ntile = fs >> 1, kstep = fs & 1;
        int k = kstep * 32 + (l >> 4) * 8 + e;
        int j = ntile * 16 + (l & 15);
        float v = W1[(64 + k) * H + j] - W1[(128 + k) * H + j];
        __hip_bfloat16 hv = __float2bfloat16(v);
        reinterpret_cast<unsigned short*>(ws + 131072)[m] =
            __builtin_bit_cast(unsigned short, hv);
    } else {                               // zero num+den: 266240 floats = 66560 float4
        int z = (blk - 520) * 256 + tid;
        float4 zz = {0.f, 0.f, 0.f, 0.f};
        reinterpret_cast<float4*>(ws + 132096)[z] = zz;
    }
}

__device__ __forceinline__ unsigned short bf16u(float x) {
    __hip_bfloat16 h = __float2bfloat16(x);
    return __builtin_bit_cast(unsigned short, h);
}

__global__ __launch_bounds__(256) void attn_pool_kernel(
        const float* __restrict__ keys,   // [B,T,D] fp32
        const int*   __restrict__ mask,   // [B,T]
        const unsigned short* __restrict__ wkf, // 2048 bf16 B-fragments
        const float* __restrict__ qa_all, // [B,32]
        const float* __restrict__ W2,     // [32]
        float*       __restrict__ num,    // [B,64] zero-initialized
        float*       __restrict__ den)    // [B]    zero-initialized
{
    __shared__ float wkbuf[4][16 * PITCH];    // 4 x 4352 B, wave-private slabs

    const int tid  = threadIdx.x;
    const int wv   = tid >> 6;
    const int lane = tid & 63;
    const int quad = lane >> 4;
    const int l15  = lane & 15;

    const int gid  = blockIdx.x * 4 + wv;               // 0 .. 53247
    const int b    = (int)(((unsigned)gid * 20165u) >> 18);   // gid / 13 (exact for gid<2^18-ish)
    const int tile = gid - b * NTILE;

    // Wk B-fragments (L2-broadcast) + per-b qa / W2
    const short8* wf = reinterpret_cast<const short8*>(wkf);
    short8 bf0 = wf[0 * 64 + lane];
    short8 bf1 = wf[1 * 64 + lane];
    short8 bf2 = wf[2 * 64 + lane];
    short8 bf3 = wf[3 * 64 + lane];

    const float* qa = qa_all + (size_t)b * H;
    const float qa0 = qa[l15];
    const float qa1 = qa[16 + l15];
    const float w20 = W2[l15];
    const float w21 = W2[16 + l15];

    const int t  = tile * 16 + l15;
    const int tr = (t < T) ? t : (T - 1);               // clamp pad rows (weight forced 0)

    const float4* krow = reinterpret_cast<const float4*>(keys + (size_t)b * (T * D));
    float4 k0 = krow[tr * 16 + quad * 2 + 0];
    float4 k1 = krow[tr * 16 + quad * 2 + 1];
    float4 k2 = krow[tr * 16 + 8 + quad * 2 + 0];
    float4 k3 = krow[tr * 16 + 8 + quad * 2 + 1];
    const int mval = mask[(size_t)b * T + tr];

    // bf16 A-fragments: A[m=l15][k=quad*8+e], second frag k+32
    short8 a0, a1;
    a0[0] = (short)bf16u(k0.x); a0[1] = (short)bf16u(k0.y);
    a0[2] = (short)bf16u(k0.z); a0[3] = (short)bf16u(k0.w);
    a0[4] = (short)bf16u(k1.x); a0[5] = (short)bf16u(k1.y);
    a0[6] = (short)bf16u(k1.z); a0[7] = (short)bf16u(k1.w);
    a1[0] = (short)bf16u(k2.x); a1[1] = (short)bf16u(k2.y);
    a1[2] = (short)bf16u(k2.z); a1[3] = (short)bf16u(k2.w);
    a1[4] = (short)bf16u(k3.x); a1[5] = (short)bf16u(k3.y);
    a1[6] = (short)bf16u(k3.z); a1[7] = (short)bf16u(k3.w);

    f32x4 c0 = {0.f, 0.f, 0.f, 0.f};
    f32x4 c1 = {0.f, 0.f, 0.f, 0.f};
    c0 = __builtin_amdgcn_mfma_f32_16x16x32_bf16(a0, bf0, c0, 0, 0, 0);
    c0 = __builtin_amdgcn_mfma_f32_16x16x32_bf16(a1, bf1, c0, 0, 0, 0);
    c1 = __builtin_amdgcn_mfma_f32_16x16x32_bf16(a0, bf2, c1, 0, 0, 0);
    c1 = __builtin_amdgcn_mfma_f32_16x16x32_bf16(a1, bf3, c1, 0, 0, 0);

    // sigmoid + W2 contraction; D layout: row t' = quad*4+r, col j = l15
    float p[4];
    #pragma unroll
    for (int r = 0; r < 4; ++r) {
        float x0 = c0[r] + qa0;
        float x1 = c1[r] + qa1;
        float s0 = __builtin_amdgcn_rcpf(1.0f + exp2f(-x0 * LOG2E));
        float s1 = __builtin_amdgcn_rcpf(1.0f + exp2f(-x1 * LOG2E));
        p[r] = fmaf(s0, w20, s1 * w21);
    }
    #pragma unroll
    for (int r = 0; r < 4; ++r) {
        #pragma unroll
        for (int off = 1; off <= 8; off <<= 1)
            p[r] += __shfl_xor(p[r], off, 64);          // reduce over 16 j-lanes
    }
    // route score[t'=l15] to the lane holding row t' (verified R4)
    const int addr = (l15 >> 2) << 6;
    int q0 = __builtin_amdgcn_ds_bpermute(addr, __builtin_bit_cast(int, p[0]));
    int q1 = __builtin_amdgcn_ds_bpermute(addr, __builtin_bit_cast(int, p[1]));
    int q2 = __builtin_amdgcn_ds_bpermute(addr, __builtin_bit_cast(int, p[2]));
    int q3 = __builtin_amdgcn_ds_bpermute(addr, __builtin_bit_cast(int, p[3]));
    const int rsel = l15 & 3;
    int s01 = (rsel & 1) ? q1 : q0;
    int s23 = (rsel & 1) ? q3 : q2;
    float st = __builtin_bit_cast(float, (rsel & 2) ? s23 : s01);

    const float w = ((t < T) && (mval != 0)) ? exp2f((st - SOFF) * LOG2E) : 0.0f;

    // w * k into this wave's LDS slab, layout [t_local=l15][d], pitch 68
    float* wb = wkbuf[wv];
    float4 wk0 = {w * k0.x, w * k0.y, w * k0.z, w * k0.w};
    float4 wk1 = {w * k1.x, w * k1.y, w * k1.z, w * k1.w};
    float4 wk2 = {w * k2.x, w * k2.y, w * k2.z, w * k2.w};
    float4 wk3 = {w * k3.x, w * k3.y, w * k3.z, w * k3.w};
    *reinterpret_cast<float4*>(&wb[l15 * PITCH + quad * 8 + 0]) = wk0;
    *reinterpret_cast<float4*>(&wb[l15 * PITCH + quad * 8 + 4]) = wk1;
    *reinterpret_cast<float4*>(&wb[l15 * PITCH + 32 + quad * 8 + 0]) = wk2;
    *reinterpret_cast<float4*>(&wb[l15 * PITCH + 32 + quad * 8 + 4]) = wk3;

    // denominator: reduce w over the 16 t-lanes (same value in all quads)
    float dw = w;
    #pragma unroll
    for (int off = 1; off <= 8; off <<= 1)
        dw += __shfl_xor(dw, off, 64);

    // column sum over the 16 rows of this tile: lane <-> d (intra-wave LDS RAW,
    // compiler inserts lgkmcnt; banks (4t+d)%32 -> 2 lanes/bank, conflict-free)
    float colsum = 0.0f;
    #pragma unroll
    for (int tt = 0; tt < 16; ++tt)
        colsum += wb[tt * PITCH + lane];

    atomicAdd(&num[(size_t)b * D + lane], colsum);      // 64 lanes, coalesced
    if (lane == 0) atomicAdd(&den[b], dw);
}

__global__ __launch_bounds__(256) void finalize_kernel(
        const float* __restrict__ num, const float* __restrict__ den,
        float* __restrict__ out)
{
    int i = blockIdx.x * 256 + threadIdx.x;             // < B*D
    out[i] = num[i] * __builtin_amdgcn_rcpf(den[i >> 6]);
}

extern "C" void kernel_launch(void* const* d_in, const int* in_sizes, int n_in,
                              void* d_out, int out_size, void* d_ws, size_t ws_size,
                              hipStream_t stream) {
    const float* query = (const float*)d_in[0];
    const float* keys  = (const float*)d_in[1];
    const int*   mask  = (const int*)d_in[2];
    const float* W1    = (const float*)d_in[3];
    const float* b1    = (const float*)d_in[4];
    const float* W2    = (const float*)d_in[5];
    // d_in[6] = b2: softmax-invariant, unused.

    float* ws = (float*)d_ws;
    float* qa = ws;                                            // [B*32]
    unsigned short* wkf = (unsigned short*)(ws + 131072);      // 2048 bf16
    float* num = ws + 132096;                                  // [B*64]
    float* den = ws + 132096 + 262144;                         // [B]

    prep_kernel<<<780, 256, 0, stream>>>(W1, b1, query, ws);
    attn_pool_kernel<<<(B * NTILE) / 4, 256, 0, stream>>>(keys, mask, wkf, qa, W2,
                                                          num, den);
    finalize_kernel<<<(B * D) / 256, 256, 0, stream>>>(num, den, (float*)d_out);
}